// Round 2
// baseline (988.696 us; speedup 1.0000x reference)
//
#include <hip/hip_runtime.h>

// BipartiteGNN: 3-layer bipartite SAGEConv + global mean pool + linear.
// NS=NT=100000, E=1.6M per direction, F=H=64.
//
// R9 == R8 resubmit (R8 bench was an infra failure: "container failed
// twice", no counters). Audit found no OOB/hang/LDS-overflow candidate.
//
// R8: fuses agg_kernel + fgemm_kernel into conv_kernel. agg's A output
// row n depends only on node n's CSR segment, so one 256-thread block owns
// 64 dst nodes: 4 waves gather mean-aggregates (16 nodes each, sequential)
// straight into the LDS x-tile in f32 (no bf16 round-trip through HBM:
// saves 12.5 MB write + 12.8 MB read per layer-direction), then the proven
// dual-GEMM tile runs in the same kernel — its VALU work hides under the
// gather's L2-miss latency (agg showed VALUBusy only 38%). Gather groups
// widened 4x16 -> 8x8 lanes (uint4 = 16B/lane, 8 rows in flight/wave) to
// compensate for occupancy dropping 22 -> 12 waves/CU (52 KB LDS/block).
// Last layer: outputs feed only global mean pool, so the epilogue reduces
// into pooled[] directly and skips the Y write (pool_kernel eliminated).
// All __shfl trip counts remain wave-uniform (R7 discipline).

#define FDIM 64

__device__ __forceinline__ unsigned short f2bf(float f) {
  unsigned int u = __float_as_uint(f);
  unsigned int r = u + 0x7FFFu + ((u >> 16) & 1u);  // round-to-nearest-even
  return (unsigned short)(r >> 16);
}
__device__ __forceinline__ float bf2f(unsigned short h) {
  return __uint_as_float((unsigned int)h << 16);
}

// ---------------- CSR build (bucketed, atomic-free at global scope) ----------------

// Pass 1: per-block histogram over dst>>8 buckets. Block = 4096 edges.
__global__ __launch_bounds__(256) void bucket_hist_kernel(const int* __restrict__ dst,
                                                          int* __restrict__ H, int E, int NB) {
  __shared__ int lh[512];
  int t = threadIdx.x;
  lh[t] = 0;
  lh[t + 256] = 0;
  __syncthreads();
  int base = blockIdx.x * 4096;
#pragma unroll
  for (int i = 0; i < 16; ++i) {
    int e = base + i * 256 + t;
    if (e < E) atomicAdd(&lh[dst[e] >> 8], 1);
  }
  __syncthreads();
  int* row = H + (size_t)blockIdx.x * NB;
  if (t < NB) row[t] = lh[t];
  if (t + 256 < NB) row[t + 256] = lh[t + 256];
}

// Pass 2a: for each bucket k (one block), exclusive-scan H[:,k] over B rows
// in place; tot[k] = column total.  B <= 512.
__global__ __launch_bounds__(256) void colscan_kernel(int* __restrict__ H, int* __restrict__ tot,
                                                      int B, int NB) {
  __shared__ int sh[512];
  int k = blockIdx.x;
  int t = threadIdx.x;
  int v0 = (t < B) ? H[(size_t)t * NB + k] : 0;
  int v1 = (t + 256 < B) ? H[(size_t)(t + 256) * NB + k] : 0;
  sh[t] = v0;
  sh[t + 256] = v1;
  __syncthreads();
  for (int d = 1; d < 512; d <<= 1) {
    int a0 = (t >= d) ? sh[t - d] : 0;
    int a1 = (t + 256 >= d) ? sh[t + 256 - d] : 0;
    __syncthreads();
    sh[t] += a0;
    sh[t + 256] += a1;
    __syncthreads();
  }
  if (t < B) H[(size_t)t * NB + k] = sh[t] - v0;               // exclusive
  if (t + 256 < B) H[(size_t)(t + 256) * NB + k] = sh[t + 256] - v1;
  if (t == 0) tot[k] = sh[511];
}

// Pass 2b: exclusive scan of bucket totals -> boff.  NB <= 512, one block.
__global__ __launch_bounds__(256) void totscan_kernel(const int* __restrict__ tot,
                                                      int* __restrict__ boff, int NB) {
  __shared__ int sh[512];
  int t = threadIdx.x;
  sh[t] = (t < NB) ? tot[t] : 0;
  sh[t + 256] = (t + 256 < NB) ? tot[t + 256] : 0;
  __syncthreads();
  for (int d = 1; d < 512; d <<= 1) {
    int a0 = (t >= d) ? sh[t - d] : 0;
    int a1 = (t + 256 >= d) ? sh[t + 256 - d] : 0;
    __syncthreads();
    sh[t] += a0;
    sh[t + 256] += a1;
    __syncthreads();
  }
  if (t < NB) boff[t] = (t > 0) ? sh[t - 1] : 0;
  if (t + 256 < NB) boff[t + 256] = sh[t + 255];
}

// Pass 3: scatter edges into bucket-grouped order. LDS cursors hold global
// positions (base = H[block][k] + boff[k]); writes land in short runs.
// Entry packed: (src << 8) | (dst & 255)  [src < 2^17, build needs dst&255]
__global__ __launch_bounds__(256) void bin_kernel(const int* __restrict__ src,
                                                  const int* __restrict__ dst,
                                                  const int* __restrict__ H,
                                                  const int* __restrict__ boff,
                                                  int* __restrict__ binned, int E, int NB) {
  __shared__ int cur[512];
  int t = threadIdx.x;
  const int* row = H + (size_t)blockIdx.x * NB;
  if (t < NB) cur[t] = row[t] + boff[t];
  if (t + 256 < NB) cur[t + 256] = row[t + 256] + boff[t + 256];
  __syncthreads();
  int base = blockIdx.x * 4096;
#pragma unroll
  for (int i = 0; i < 16; ++i) {
    int e = base + i * 256 + t;
    if (e < E) {
      int d = dst[e];
      int p = atomicAdd(&cur[d >> 8], 1);  // LDS atomic
      binned[p] = (src[e] << 8) | (d & 255);
    }
  }
}

// Pass 4: one block per bucket -> local hist/scan/rank, contiguous CSR slab.
__global__ __launch_bounds__(256) void build_kernel(const int* __restrict__ binned,
                                                    const int* __restrict__ boff,
                                                    int* __restrict__ off, int* __restrict__ csr,
                                                    float* __restrict__ inv_deg,
                                                    int N, int NB, int E) {
  __shared__ int cnt[256];
  __shared__ int lofs[256];
  __shared__ int cur[256];
  int b = blockIdx.x, t = threadIdx.x;
  int n0 = b << 8;
  cnt[t] = 0;
  __syncthreads();
  int s0 = boff[b];
  int s1 = (b + 1 < NB) ? boff[b + 1] : E;
  for (int i = s0 + t; i < s1; i += 256) {
    atomicAdd(&cnt[binned[i] & 255], 1);  // LDS atomic
  }
  __syncthreads();
  int c = cnt[t];
  lofs[t] = c;
  __syncthreads();
  for (int d = 1; d < 256; d <<= 1) {
    int v = (t >= d) ? lofs[t - d] : 0;
    __syncthreads();
    lofs[t] += v;
    __syncthreads();
  }
  int excl = lofs[t] - c;
  cur[t] = s0 + excl;
  int node = n0 + t;
  if (node < N) {
    off[node] = s0 + excl;
    inv_deg[node] = 1.0f / (float)max(c, 1);
    if (node == N - 1) off[N] = s0 + excl + c;
  }
  __syncthreads();
  for (int i = s0 + t; i < s1; i += 256) {
    int e = binned[i];
    int r = atomicAdd(&cur[e & 255], 1);  // LDS atomic
    csr[r] = e >> 8;
  }
}

// ---------------- fp32 -> bf16 pack ----------------

__global__ void pack_kernel(const float* __restrict__ X, unsigned short* __restrict__ Y, int n4) {
  int i = blockIdx.x * 256 + threadIdx.x;
  if (i < n4) {
    float4 v = ((const float4*)X)[i];
    uint2 pk;
    pk.x = (unsigned int)f2bf(v.x) | ((unsigned int)f2bf(v.y) << 16);
    pk.y = (unsigned int)f2bf(v.z) | ((unsigned int)f2bf(v.w) << 16);
    ((uint2*)Y)[i] = pk;
  }
}

// ---------------- fused conv: gather-mean + dual GEMM (+ last-layer pool) ----------------
// Block = 256 threads = 4 waves, owns 64 dst nodes. Each wave gathers 16
// nodes sequentially: 8 groups of 8 lanes, each group loads one edge row
// per iteration as uint4 (16B/lane), inner trip count wave-uniform so every
// __shfl sees all 64 lanes active. Mean rows land in xsh as f32. Then the
// R3-proven dual register-tile GEMM (Wl on agg, Wr on Xd) runs from LDS.

__global__ __launch_bounds__(256) void conv_kernel(const unsigned short* __restrict__ Msg,
                                                   const unsigned short* __restrict__ Xd,
                                                   const int* __restrict__ off,
                                                   const int* __restrict__ csr,
                                                   const float* __restrict__ Wl,
                                                   const float* __restrict__ Wr,
                                                   const float* __restrict__ bias,
                                                   unsigned short* __restrict__ Y,
                                                   float* __restrict__ pooled,
                                                   int N, int lastLayer) {
  __shared__ __align__(16) float wt[128][68];  // wt[k][h]=Wl[h][k]; wt[64+k][h]=Wr[h][k]
  __shared__ __align__(16) float xsh[64][68];  // f32 tile: agg rows, then Xd rows
  __shared__ float pacc[64];
  int t = threadIdx.x;
  for (int i = t; i < 4096; i += 256) {
    int h = i >> 6, k = i & 63;
    wt[k][h] = Wl[i];
    wt[64 + k][h] = Wr[i];
  }
  if (lastLayer && t < 64) pacc[t] = 0.f;

  int n0 = blockIdx.x * 64;
  int wid = t >> 6, lane = t & 63;
  int g = lane >> 3;   // edge group 0..7
  int fl = lane & 7;   // 16B feature chunk: features [fl*8, fl*8+8)
  int w0 = n0 + wid * 16;
  // prefetch this wave's 17 CSR offsets (lanes 0..16), clamped to off[N]
  int oi = w0 + ((lane < 17) ? lane : 16);
  int offv = off[min(oi, N)];

  for (int i = 0; i < 16; ++i) {
    int s0 = __shfl(offv, i, 64);       // wave-uniform
    int s1 = __shfl(offv, i + 1, 64);   // (node >= N  =>  s0 == s1 == off[N])
    float a0 = 0.f, a1 = 0.f, a2 = 0.f, a3 = 0.f;
    float a4 = 0.f, a5 = 0.f, a6 = 0.f, a7 = 0.f;
    for (int base = s0; base < s1; base += 64) {
      int idx = base + lane;
      int mysrc = (idx < s1) ? csr[idx] : 0;
      int m = min(64, s1 - base);
      int kmax = (m + 7) >> 3;  // wave-uniform
      for (int k = 0; k < kmax; ++k) {
        int j = g + 8 * k;
        int s = __shfl(mysrc, (j < m) ? j : 0, 64);  // all 64 lanes active
        if (j < m) {
          uint4 v = *((const uint4*)(Msg + (size_t)s * 64) + fl);
          a0 += bf2f((unsigned short)(v.x & 0xffffu));
          a1 += bf2f((unsigned short)(v.x >> 16));
          a2 += bf2f((unsigned short)(v.y & 0xffffu));
          a3 += bf2f((unsigned short)(v.y >> 16));
          a4 += bf2f((unsigned short)(v.z & 0xffffu));
          a5 += bf2f((unsigned short)(v.z >> 16));
          a6 += bf2f((unsigned short)(v.w & 0xffffu));
          a7 += bf2f((unsigned short)(v.w >> 16));
        }
      }
    }
    // fold groups 4..7 into 0..3, 2..3 into 0..1, 1 into 0 (all lanes active)
    a0 += __shfl_down(a0, 32, 64); a1 += __shfl_down(a1, 32, 64);
    a2 += __shfl_down(a2, 32, 64); a3 += __shfl_down(a3, 32, 64);
    a4 += __shfl_down(a4, 32, 64); a5 += __shfl_down(a5, 32, 64);
    a6 += __shfl_down(a6, 32, 64); a7 += __shfl_down(a7, 32, 64);
    a0 += __shfl_down(a0, 16, 64); a1 += __shfl_down(a1, 16, 64);
    a2 += __shfl_down(a2, 16, 64); a3 += __shfl_down(a3, 16, 64);
    a4 += __shfl_down(a4, 16, 64); a5 += __shfl_down(a5, 16, 64);
    a6 += __shfl_down(a6, 16, 64); a7 += __shfl_down(a7, 16, 64);
    a0 += __shfl_down(a0, 8, 64);  a1 += __shfl_down(a1, 8, 64);
    a2 += __shfl_down(a2, 8, 64);  a3 += __shfl_down(a3, 8, 64);
    a4 += __shfl_down(a4, 8, 64);  a5 += __shfl_down(a5, 8, 64);
    a6 += __shfl_down(a6, 8, 64);  a7 += __shfl_down(a7, 8, 64);
    if (lane < 8) {
      float id = (s1 > s0) ? (1.0f / (float)(s1 - s0)) : 0.f;
      int row = wid * 16 + i;
      *(float4*)&xsh[row][lane * 8] = make_float4(a0 * id, a1 * id, a2 * id, a3 * id);
      *(float4*)&xsh[row][lane * 8 + 4] = make_float4(a4 * id, a5 * id, a6 * id, a7 * id);
    }
  }
  __syncthreads();

  int ng = t >> 4;
  int h0 = (t & 15) * 4;
  float acc[4][4];
  float b0 = bias[h0], b1 = bias[h0 + 1], b2 = bias[h0 + 2], b3 = bias[h0 + 3];
#pragma unroll
  for (int j = 0; j < 4; ++j) { acc[j][0] = b0; acc[j][1] = b1; acc[j][2] = b2; acc[j][3] = b3; }
  // unroll 8 (not full): full unroll of both loops spilled (VGPR=256, R3)
#pragma unroll 8
  for (int k = 0; k < 64; ++k) {
    float4 w = *(const float4*)&wt[k][h0];
#pragma unroll
    for (int j = 0; j < 4; ++j) {
      float x = xsh[ng * 4 + j][k];
      acc[j][0] += x * w.x;
      acc[j][1] += x * w.y;
      acc[j][2] += x * w.z;
      acc[j][3] += x * w.w;
    }
  }
  __syncthreads();
  // stage Xd (bf16) tile as f32
  const uint4* Xv = (const uint4*)Xd;
  for (int i = t; i < 512; i += 256) {
    int n = i >> 3, c8 = i & 7;
    uint4 v = make_uint4(0u, 0u, 0u, 0u);
    if (n0 + n < N) v = Xv[(size_t)(n0 + n) * 8 + c8];
    int c0 = c8 * 8;
    xsh[n][c0 + 0] = bf2f((unsigned short)(v.x & 0xffffu));
    xsh[n][c0 + 1] = bf2f((unsigned short)(v.x >> 16));
    xsh[n][c0 + 2] = bf2f((unsigned short)(v.y & 0xffffu));
    xsh[n][c0 + 3] = bf2f((unsigned short)(v.y >> 16));
    xsh[n][c0 + 4] = bf2f((unsigned short)(v.z & 0xffffu));
    xsh[n][c0 + 5] = bf2f((unsigned short)(v.z >> 16));
    xsh[n][c0 + 6] = bf2f((unsigned short)(v.w & 0xffffu));
    xsh[n][c0 + 7] = bf2f((unsigned short)(v.w >> 16));
  }
  __syncthreads();
#pragma unroll 8
  for (int k = 0; k < 64; ++k) {
    float4 w = *(const float4*)&wt[64 + k][h0];
#pragma unroll
    for (int j = 0; j < 4; ++j) {
      float x = xsh[ng * 4 + j][k];
      acc[j][0] += x * w.x;
      acc[j][1] += x * w.y;
      acc[j][2] += x * w.z;
      acc[j][3] += x * w.w;
    }
  }
  if (!lastLayer) {
#pragma unroll
    for (int j = 0; j < 4; ++j) {
      int n = n0 + ng * 4 + j;
      if (n < N) {
        uint2 pk;
        pk.x = (unsigned int)f2bf(acc[j][0]) | ((unsigned int)f2bf(acc[j][1]) << 16);
        pk.y = (unsigned int)f2bf(acc[j][2]) | ((unsigned int)f2bf(acc[j][3]) << 16);
        *(uint2*)(Y + (size_t)n * 64 + h0) = pk;
      }
    }
  } else {
    // last layer feeds only global mean pool: reduce in LDS, one global
    // atomicAdd per feature per block; skip the Y write entirely.
    float p0 = 0.f, p1 = 0.f, p2 = 0.f, p3 = 0.f;
#pragma unroll
    for (int j = 0; j < 4; ++j) {
      int n = n0 + ng * 4 + j;
      if (n < N) { p0 += acc[j][0]; p1 += acc[j][1]; p2 += acc[j][2]; p3 += acc[j][3]; }
    }
    atomicAdd(&pacc[h0 + 0], p0);
    atomicAdd(&pacc[h0 + 1], p1);
    atomicAdd(&pacc[h0 + 2], p2);
    atomicAdd(&pacc[h0 + 3], p3);
    __syncthreads();
    if (t < 64) atomicAdd(&pooled[t], pacc[t]);
  }
}

// ---------------- final linear ----------------

__global__ void final_kernel(const float* __restrict__ pooled, const float* __restrict__ linW,
                             const float* __restrict__ linb, float* __restrict__ out, float invM) {
  int t = threadIdx.x;  // 64 threads
  float v = pooled[t] * invM * linW[t];
#pragma unroll
  for (int o = 32; o > 0; o >>= 1) v += __shfl_down(v, o, 64);
  if (t == 0) out[0] = v + linb[0];
}

// ---------------- launch ----------------

extern "C" void kernel_launch(void* const* d_in, const int* in_sizes, int n_in,
                              void* d_out, int out_size, void* d_ws, size_t ws_size,
                              hipStream_t stream) {
  const float* x_source = (const float*)d_in[0];
  const float* x_target = (const float*)d_in[1];
  float* scratchA = (float*)d_in[2];  // edge_attr_s2t: 12.8M floats, unused input
  float* scratchB = (float*)d_in[3];  // edge_attr_t2s: 12.8M floats, unused input
  const float* W_l_s2t = (const float*)d_in[4];
  const float* b_s2t   = (const float*)d_in[5];
  const float* W_r_s2t = (const float*)d_in[6];
  const float* W_l_t2s = (const float*)d_in[7];
  const float* b_t2s   = (const float*)d_in[8];
  const float* W_r_t2s = (const float*)d_in[9];
  const float* lin_W   = (const float*)d_in[10];
  const float* lin_b   = (const float*)d_in[11];
  const int* ei_s2t    = (const int*)d_in[12];
  const int* ei_t2s    = (const int*)d_in[13];

  const int NS = in_sizes[0] / FDIM;
  const int NT = in_sizes[1] / FDIM;
  const int E  = in_sizes[12] / 2;
  const int L  = in_sizes[4] / (FDIM * FDIM);
  const size_t NF = (size_t)NS * FDIM;  // NS==NT==100000

  // scratchA layout: csr_t, csr_s, off/inv meta, S0, T0
  int*   csr_t  = (int*)scratchA;             // E
  int*   csr_s  = csr_t + E;                  // E
  float* inv_t  = (float*)(csr_s + E);        // NS
  float* inv_s  = inv_t + NS;                 // NS
  int*   off_t  = (int*)(inv_s + NS);         // NS+1
  int*   off_s  = off_t + NS + 1;             // NS+1
  unsigned short* S0 = (unsigned short*)(off_s + NS + 2);  // NF bf16
  unsigned short* T0 = S0 + NF;                            // NF bf16
  // scratchB layout: S1, T1, binned, H, tot, boff
  unsigned short* S1 = (unsigned short*)scratchB;          // NF bf16
  unsigned short* T1 = S1 + NF;                            // NF bf16
  int*  binned = (int*)(T1 + NF);                          // E ints (packed)
  int*  H      = binned + E;                               // B*NB
  // d_ws layout: pooled
  float* pooled = (float*)d_ws;

  const int* src_s2t = ei_s2t;
  const int* dst_s2t = ei_s2t + E;
  const int* src_t2s = ei_t2s;
  const int* dst_t2s = ei_t2s + E;

  const int NB_T = (NT + 255) >> 8;          // dst buckets (target space)
  const int NB_S = (NS + 255) >> 8;          // dst buckets (source space)
  const int B    = (E + 4095) >> 12;         // edge chunks of 4096
  int* tot  = H + (size_t)B * ((NB_T > NB_S) ? NB_T : NB_S);  // max(NB)
  int* boff = tot + 512;

  // --- CSR build, s2t (dst in target space) ---
  bucket_hist_kernel<<<B, 256, 0, stream>>>(dst_s2t, H, E, NB_T);
  colscan_kernel<<<NB_T, 256, 0, stream>>>(H, tot, B, NB_T);
  totscan_kernel<<<1, 256, 0, stream>>>(tot, boff, NB_T);
  bin_kernel<<<B, 256, 0, stream>>>(src_s2t, dst_s2t, H, boff, binned, E, NB_T);
  build_kernel<<<NB_T, 256, 0, stream>>>(binned, boff, off_t, csr_t, inv_t, NT, NB_T, E);

  // --- CSR build, t2s (dst in source space) ---
  bucket_hist_kernel<<<B, 256, 0, stream>>>(dst_t2s, H, E, NB_S);
  colscan_kernel<<<NB_S, 256, 0, stream>>>(H, tot, B, NB_S);
  totscan_kernel<<<1, 256, 0, stream>>>(tot, boff, NB_S);
  bin_kernel<<<B, 256, 0, stream>>>(src_t2s, dst_t2s, H, boff, binned, E, NB_S);
  build_kernel<<<NB_S, 256, 0, stream>>>(binned, boff, off_s, csr_s, inv_s, NS, NB_S, E);

  // --- initial bf16 pack of layer-0 inputs ---
  int gP = (int)((NF / 4 + 255) / 256);
  pack_kernel<<<gP, 256, 0, stream>>>(x_source, S0, (int)(NF / 4));
  pack_kernel<<<gP, 256, 0, stream>>>(x_target, T0, (int)(NF / 4));

  // pooled accumulated by last-layer conv epilogues
  hipMemsetAsync(pooled, 0, 64 * 4, stream);

  unsigned short* xs_in = S0;
  unsigned short* xt_in = T0;
  unsigned short* xs_out = S1;
  unsigned short* xt_out = T1;

  int gS = (NS + 63) / 64;
  int gT = (NT + 63) / 64;

  for (int l = 0; l < L; ++l) {
    const float* Wl1 = W_l_s2t + (size_t)l * 4096;
    const float* Wr1 = W_r_s2t + (size_t)l * 4096;
    const float* bb1 = b_s2t + (size_t)l * 64;
    const float* Wl2 = W_l_t2s + (size_t)l * 4096;
    const float* Wr2 = W_r_t2s + (size_t)l * 4096;
    const float* bb2 = b_t2s + (size_t)l * 64;
    int last = (l == L - 1) ? 1 : 0;

    // conv s2t -> new xt: Y = mean_agg(xs)@Wl1^T + xt@Wr1^T + b1
    conv_kernel<<<gT, 256, 0, stream>>>(xs_in, xt_in, off_t, csr_t, Wl1, Wr1, bb1,
                                        xt_out, pooled, NT, last);
    // conv t2s -> new xs: Y = mean_agg(xt_old)@Wl2^T + xs_old@Wr2^T + b2
    conv_kernel<<<gS, 256, 0, stream>>>(xt_in, xs_in, off_s, csr_s, Wl2, Wr2, bb2,
                                        xs_out, pooled, NS, last);

    // swap ping-pong
    unsigned short* ts = xs_in; xs_in = xs_out; xs_out = ts;
    unsigned short* tt = xt_in; xt_in = xt_out; xt_out = tt;
  }

  final_kernel<<<1, 64, 0, stream>>>(pooled, lin_W, lin_b, (float*)d_out,
                                     1.0f / (float)(NS + NT));
}

// Round 3
// 786.921 us; speedup vs baseline: 1.2564x; 1.2564x over previous
//
#include <hip/hip_runtime.h>

// BipartiteGNN: 3-layer bipartite SAGEConv + global mean pool + linear.
// NS=NT=100000, E=1.6M per direction, F=H=64.
//
// R10: R8's fusion regressed (conv 135 µs: occupancy 23%, gather BW 1.15
// vs 3.0 TB/s — latency-starved). Timestamp arithmetic also showed R7's
// fgemm was ~56 µs/dispatch (LDS-bound fp32 VALU at 3 blocks/CU, ~20% of
// the wrong pipe's peak). So: revert gather to the proven R7 agg_kernel
// (55 µs, occ 70%) and replace fgemm with an MFMA GEMM:
//   Y = A@Wl^T + Xd@Wr^T + b  ==  [A|Xd](M x 128) @ [Wl;Wr]^T(128 x 64)
// via mfma_f32_16x16x32_bf16. Weights bf16-packed once per launch. No LDS
// in the GEMM: B-frags in registers (8 KB weights, L2-hot), A rows stream
// as 16 B/lane. Operand layout = verified symmetric "B^T input" pattern
// (lane&15=row, (lane>>4)*8+j=k; within-lane k-permutation cancels since
// A and B map identically). C/D: col=lane&15, row=(lane>>4)*4+reg.
// Last layer keeps R8's pooled epilogue (no Y write, no pool_kernel).
// Scratch layouts reordered so all bf16 feature buffers are 16B-aligned.

#define FDIM 64

typedef short bh8 __attribute__((ext_vector_type(8)));  // 8 bf16 = 4 VGPR
typedef float fx4 __attribute__((ext_vector_type(4)));  // MFMA accumulator

__device__ __forceinline__ unsigned short f2bf(float f) {
  unsigned int u = __float_as_uint(f);
  unsigned int r = u + 0x7FFFu + ((u >> 16) & 1u);  // round-to-nearest-even
  return (unsigned short)(r >> 16);
}
__device__ __forceinline__ float bf2f(unsigned short h) {
  return __uint_as_float((unsigned int)h << 16);
}

// ---------------- CSR build (bucketed, atomic-free at global scope) ----------------

// Pass 1: per-block histogram over dst>>8 buckets. Block = 4096 edges.
__global__ __launch_bounds__(256) void bucket_hist_kernel(const int* __restrict__ dst,
                                                          int* __restrict__ H, int E, int NB) {
  __shared__ int lh[512];
  int t = threadIdx.x;
  lh[t] = 0;
  lh[t + 256] = 0;
  __syncthreads();
  int base = blockIdx.x * 4096;
#pragma unroll
  for (int i = 0; i < 16; ++i) {
    int e = base + i * 256 + t;
    if (e < E) atomicAdd(&lh[dst[e] >> 8], 1);
  }
  __syncthreads();
  int* row = H + (size_t)blockIdx.x * NB;
  if (t < NB) row[t] = lh[t];
  if (t + 256 < NB) row[t + 256] = lh[t + 256];
}

// Pass 2a: for each bucket k (one block), exclusive-scan H[:,k] over B rows
// in place; tot[k] = column total.  B <= 512.
__global__ __launch_bounds__(256) void colscan_kernel(int* __restrict__ H, int* __restrict__ tot,
                                                      int B, int NB) {
  __shared__ int sh[512];
  int k = blockIdx.x;
  int t = threadIdx.x;
  int v0 = (t < B) ? H[(size_t)t * NB + k] : 0;
  int v1 = (t + 256 < B) ? H[(size_t)(t + 256) * NB + k] : 0;
  sh[t] = v0;
  sh[t + 256] = v1;
  __syncthreads();
  for (int d = 1; d < 512; d <<= 1) {
    int a0 = (t >= d) ? sh[t - d] : 0;
    int a1 = (t + 256 >= d) ? sh[t + 256 - d] : 0;
    __syncthreads();
    sh[t] += a0;
    sh[t + 256] += a1;
    __syncthreads();
  }
  if (t < B) H[(size_t)t * NB + k] = sh[t] - v0;               // exclusive
  if (t + 256 < B) H[(size_t)(t + 256) * NB + k] = sh[t + 256] - v1;
  if (t == 0) tot[k] = sh[511];
}

// Pass 2b: exclusive scan of bucket totals -> boff.  NB <= 512, one block.
__global__ __launch_bounds__(256) void totscan_kernel(const int* __restrict__ tot,
                                                      int* __restrict__ boff, int NB) {
  __shared__ int sh[512];
  int t = threadIdx.x;
  sh[t] = (t < NB) ? tot[t] : 0;
  sh[t + 256] = (t + 256 < NB) ? tot[t + 256] : 0;
  __syncthreads();
  for (int d = 1; d < 512; d <<= 1) {
    int a0 = (t >= d) ? sh[t - d] : 0;
    int a1 = (t + 256 >= d) ? sh[t + 256 - d] : 0;
    __syncthreads();
    sh[t] += a0;
    sh[t + 256] += a1;
    __syncthreads();
  }
  if (t < NB) boff[t] = (t > 0) ? sh[t - 1] : 0;
  if (t + 256 < NB) boff[t + 256] = sh[t + 255];
}

// Pass 3: scatter edges into bucket-grouped order. LDS cursors hold global
// positions (base = H[block][k] + boff[k]); writes land in short runs.
// Entry packed: (src << 8) | (dst & 255)  [src < 2^17, build needs dst&255]
__global__ __launch_bounds__(256) void bin_kernel(const int* __restrict__ src,
                                                  const int* __restrict__ dst,
                                                  const int* __restrict__ H,
                                                  const int* __restrict__ boff,
                                                  int* __restrict__ binned, int E, int NB) {
  __shared__ int cur[512];
  int t = threadIdx.x;
  const int* row = H + (size_t)blockIdx.x * NB;
  if (t < NB) cur[t] = row[t] + boff[t];
  if (t + 256 < NB) cur[t + 256] = row[t + 256] + boff[t + 256];
  __syncthreads();
  int base = blockIdx.x * 4096;
#pragma unroll
  for (int i = 0; i < 16; ++i) {
    int e = base + i * 256 + t;
    if (e < E) {
      int d = dst[e];
      int p = atomicAdd(&cur[d >> 8], 1);  // LDS atomic
      binned[p] = (src[e] << 8) | (d & 255);
    }
  }
}

// Pass 4: one block per bucket -> local hist/scan/rank, contiguous CSR slab.
__global__ __launch_bounds__(256) void build_kernel(const int* __restrict__ binned,
                                                    const int* __restrict__ boff,
                                                    int* __restrict__ off, int* __restrict__ csr,
                                                    float* __restrict__ inv_deg,
                                                    int N, int NB, int E) {
  __shared__ int cnt[256];
  __shared__ int lofs[256];
  __shared__ int cur[256];
  int b = blockIdx.x, t = threadIdx.x;
  int n0 = b << 8;
  cnt[t] = 0;
  __syncthreads();
  int s0 = boff[b];
  int s1 = (b + 1 < NB) ? boff[b + 1] : E;
  for (int i = s0 + t; i < s1; i += 256) {
    atomicAdd(&cnt[binned[i] & 255], 1);  // LDS atomic
  }
  __syncthreads();
  int c = cnt[t];
  lofs[t] = c;
  __syncthreads();
  for (int d = 1; d < 256; d <<= 1) {
    int v = (t >= d) ? lofs[t - d] : 0;
    __syncthreads();
    lofs[t] += v;
    __syncthreads();
  }
  int excl = lofs[t] - c;
  cur[t] = s0 + excl;
  int node = n0 + t;
  if (node < N) {
    off[node] = s0 + excl;
    inv_deg[node] = 1.0f / (float)max(c, 1);
    if (node == N - 1) off[N] = s0 + excl + c;
  }
  __syncthreads();
  for (int i = s0 + t; i < s1; i += 256) {
    int e = binned[i];
    int r = atomicAdd(&cur[e & 255], 1);  // LDS atomic
    csr[r] = e >> 8;
  }
}

// ---------------- fp32 -> bf16 pack ----------------

__global__ void pack_kernel(const float* __restrict__ X, unsigned short* __restrict__ Y, int n4) {
  int i = blockIdx.x * 256 + threadIdx.x;
  if (i < n4) {
    float4 v = ((const float4*)X)[i];
    uint2 pk;
    pk.x = (unsigned int)f2bf(v.x) | ((unsigned int)f2bf(v.y) << 16);
    pk.y = (unsigned int)f2bf(v.z) | ((unsigned int)f2bf(v.w) << 16);
    ((uint2*)Y)[i] = pk;
  }
}

// ---------------- aggregation: A16[i] = inv_deg[i] * sum_{j in CSR(i)} Msg16[j] ----------------
// R7-proven: one wave per dst node; 4 groups of 16 lanes, each group gathers
// one edge row per iteration with uint2 (8B/lane) loads; cross-group shfl
// reduction. Inner trip count is wave-uniform so every __shfl sees all 64
// lanes active. 55 µs / 3.0 TB/s / occ 70% measured.

__global__ __launch_bounds__(256) void agg_kernel(const unsigned short* __restrict__ Msg,
                                                  const int* __restrict__ off,
                                                  const int* __restrict__ csr,
                                                  const float* __restrict__ inv_deg,
                                                  unsigned short* __restrict__ A, int N) {
  int w = (blockIdx.x * 256 + threadIdx.x) >> 6;
  int lane = threadIdx.x & 63;
  if (w >= N) return;
  int g = lane >> 4;    // edge group 0..3
  int fl = lane & 15;   // feature sublane: features [fl*4, fl*4+4)
  int s0 = off[w], s1 = off[w + 1];
  float ax = 0.f, ay = 0.f, az = 0.f, aw = 0.f;
  for (int base = s0; base < s1; base += 64) {
    int idx = base + lane;
    int mysrc = (idx < s1) ? csr[idx] : 0;
    int m = min(64, s1 - base);
    int kmax = (m + 3) >> 2;  // wave-uniform
    for (int k = 0; k < kmax; ++k) {
      int j = g + 4 * k;
      int s = __shfl(mysrc, (j < m) ? j : 0, 64);  // all 64 lanes active here
      if (j < m) {
        uint2 v = *((const uint2*)(Msg + (size_t)s * 64) + fl);
        ax += bf2f((unsigned short)(v.x & 0xffffu));
        ay += bf2f((unsigned short)(v.x >> 16));
        az += bf2f((unsigned short)(v.y & 0xffffu));
        aw += bf2f((unsigned short)(v.y >> 16));
      }
    }
  }
  // cross-group reduction: g0+=g2, g1+=g3; then g0+=g1
  ax += __shfl_down(ax, 32, 64);
  ay += __shfl_down(ay, 32, 64);
  az += __shfl_down(az, 32, 64);
  aw += __shfl_down(aw, 32, 64);
  ax += __shfl_down(ax, 16, 64);
  ay += __shfl_down(ay, 16, 64);
  az += __shfl_down(az, 16, 64);
  aw += __shfl_down(aw, 16, 64);
  if (g == 0) {
    float id = inv_deg[w];
    uint2 pk;
    pk.x = (unsigned int)f2bf(ax * id) | ((unsigned int)f2bf(ay * id) << 16);
    pk.y = (unsigned int)f2bf(az * id) | ((unsigned int)f2bf(aw * id) << 16);
    *((uint2*)(A + (size_t)w * 64) + fl) = pk;
  }
}

// ---------------- MFMA dual GEMM: Y = A@Wl^T + Xd@Wr^T + b ----------------
// Block = 4 waves; wave computes 16 rows x 64 h via 16x16x32 bf16 MFMA.
// A/B frags: lane&15 = row (m for A, h for W), k = (lane>>4)*8 + j within
// the 32-wide chunk — identical mapping both sides, so any within-lane
// k-permutation cancels. C/D: col=lane&15, row=(lane>>4)*4+reg (verified).
// Weights pre-packed to bf16 (8 KB, L2-hot), held in VGPRs. No LDS except
// the last-layer pool reduction.

__global__ __launch_bounds__(256) void fgemm_mfma_kernel(
    const unsigned short* __restrict__ A,    // bf16 [N][64] aggregated means
    const unsigned short* __restrict__ Xd,   // bf16 [N][64] dst features
    const unsigned short* __restrict__ Wlb,  // bf16 [64][64], row h, col k
    const unsigned short* __restrict__ Wrb,  // bf16 [64][64]
    const float* __restrict__ bias,
    unsigned short* __restrict__ Y,
    float* __restrict__ pooled,
    int N, int lastLayer) {
  __shared__ float pacc[64];
  int t = threadIdx.x;
  if (lastLayer) {
    if (t < 64) pacc[t] = 0.f;
    __syncthreads();
  }

  int wid = t >> 6, lane = t & 63;
  int lr = lane & 15;  // row within A/B tile; col within C tile
  int kg = lane >> 4;  // k-subgroup 0..3 (8 consecutive k each)
  int m0 = blockIdx.x * 64 + wid * 16;

  int mrow = m0 + lr;
  int mclamp = min(mrow, N - 1);  // garbage rows only feed unstored outputs
  const bh8* arow = (const bh8*)(A + (size_t)mclamp * 64);
  const bh8* xrow = (const bh8*)(Xd + (size_t)mclamp * 64);
  const bh8* wl = (const bh8*)Wlb;  // row h = 8 chunks of 8 bf16
  const bh8* wr = (const bh8*)Wrb;

  fx4 acc[4];
#pragma unroll
  for (int nt = 0; nt < 4; ++nt) acc[nt] = (fx4){0.f, 0.f, 0.f, 0.f};

  // phase 1: A @ Wl^T
  {
    bh8 b0[4], b1[4], a0 = arow[kg], a1 = arow[4 + kg];
#pragma unroll
    for (int nt = 0; nt < 4; ++nt) {
      b0[nt] = wl[(nt * 16 + lr) * 8 + kg];
      b1[nt] = wl[(nt * 16 + lr) * 8 + 4 + kg];
    }
#pragma unroll
    for (int nt = 0; nt < 4; ++nt)
      acc[nt] = __builtin_amdgcn_mfma_f32_16x16x32_bf16(a0, b0[nt], acc[nt], 0, 0, 0);
#pragma unroll
    for (int nt = 0; nt < 4; ++nt)
      acc[nt] = __builtin_amdgcn_mfma_f32_16x16x32_bf16(a1, b1[nt], acc[nt], 0, 0, 0);
  }
  // phase 2: Xd @ Wr^T
  {
    bh8 b0[4], b1[4], x0 = xrow[kg], x1 = xrow[4 + kg];
#pragma unroll
    for (int nt = 0; nt < 4; ++nt) {
      b0[nt] = wr[(nt * 16 + lr) * 8 + kg];
      b1[nt] = wr[(nt * 16 + lr) * 8 + 4 + kg];
    }
#pragma unroll
    for (int nt = 0; nt < 4; ++nt)
      acc[nt] = __builtin_amdgcn_mfma_f32_16x16x32_bf16(x0, b0[nt], acc[nt], 0, 0, 0);
#pragma unroll
    for (int nt = 0; nt < 4; ++nt)
      acc[nt] = __builtin_amdgcn_mfma_f32_16x16x32_bf16(x1, b1[nt], acc[nt], 0, 0, 0);
  }

  if (!lastLayer) {
#pragma unroll
    for (int nt = 0; nt < 4; ++nt) {
      int h = nt * 16 + lr;
      float bb = bias[h];
#pragma unroll
      for (int j = 0; j < 4; ++j) {
        int m = m0 + kg * 4 + j;
        if (m < N) Y[(size_t)m * 64 + h] = f2bf(acc[nt][j] + bb);
      }
    }
  } else {
    // last layer feeds only global mean pool: reduce per-h in LDS, one
    // global atomicAdd per feature per block; skip the Y write entirely.
#pragma unroll
    for (int nt = 0; nt < 4; ++nt) {
      int h = nt * 16 + lr;
      float bb = bias[h];
      float s = 0.f;
#pragma unroll
      for (int j = 0; j < 4; ++j) {
        int m = m0 + kg * 4 + j;
        if (m < N) s += acc[nt][j] + bb;
      }
      atomicAdd(&pacc[h], s);
    }
    __syncthreads();
    if (t < 64) atomicAdd(&pooled[t], pacc[t]);
  }
}

// ---------------- final linear ----------------

__global__ void final_kernel(const float* __restrict__ pooled, const float* __restrict__ linW,
                             const float* __restrict__ linb, float* __restrict__ out, float invM) {
  int t = threadIdx.x;  // 64 threads
  float v = pooled[t] * invM * linW[t];
#pragma unroll
  for (int o = 32; o > 0; o >>= 1) v += __shfl_down(v, o, 64);
  if (t == 0) out[0] = v + linb[0];
}

// ---------------- launch ----------------

extern "C" void kernel_launch(void* const* d_in, const int* in_sizes, int n_in,
                              void* d_out, int out_size, void* d_ws, size_t ws_size,
                              hipStream_t stream) {
  const float* x_source = (const float*)d_in[0];
  const float* x_target = (const float*)d_in[1];
  float* scratchA = (float*)d_in[2];  // edge_attr_s2t: 12.8M floats, unused input
  float* scratchB = (float*)d_in[3];  // edge_attr_t2s: 12.8M floats, unused input
  const float* W_l_s2t = (const float*)d_in[4];
  const float* b_s2t   = (const float*)d_in[5];
  const float* W_r_s2t = (const float*)d_in[6];
  const float* W_l_t2s = (const float*)d_in[7];
  const float* b_t2s   = (const float*)d_in[8];
  const float* W_r_t2s = (const float*)d_in[9];
  const float* lin_W   = (const float*)d_in[10];
  const float* lin_b   = (const float*)d_in[11];
  const int* ei_s2t    = (const int*)d_in[12];
  const int* ei_t2s    = (const int*)d_in[13];

  const int NS = in_sizes[0] / FDIM;
  const int NT = in_sizes[1] / FDIM;
  const int E  = in_sizes[12] / 2;
  const int L  = in_sizes[4] / (FDIM * FDIM);
  const size_t NF = (size_t)NS * FDIM;  // NS==NT==100000
  const size_t WN = (size_t)L * FDIM * FDIM;  // per weight array, elems

  // scratchA layout (16B-aligned bf16 buffers first):
  //   S0, T0 (bf16 NF each), Wb x4 (bf16 L*4096 each), csr_t, csr_s,
  //   inv_t, inv_s, off_t, off_s
  unsigned short* S0 = (unsigned short*)scratchA;          // NF bf16
  unsigned short* T0 = S0 + NF;                            // NF bf16
  unsigned short* WbLs2t = T0 + NF;                        // L*4096 bf16
  unsigned short* WbRs2t = WbLs2t + WN;
  unsigned short* WbLt2s = WbRs2t + WN;
  unsigned short* WbRt2s = WbLt2s + WN;
  int*   csr_t  = (int*)(WbRt2s + WN);        // E
  int*   csr_s  = csr_t + E;                  // E
  float* inv_t  = (float*)(csr_s + E);        // NS
  float* inv_s  = inv_t + NS;                 // NS
  int*   off_t  = (int*)(inv_s + NS);         // NS+1
  int*   off_s  = off_t + NS + 1;             // NS+1
  // scratchB layout: S1, T1 (16B-aligned), binned, H, tot, boff
  unsigned short* S1 = (unsigned short*)scratchB;          // NF bf16
  unsigned short* T1 = S1 + NF;                            // NF bf16
  int*  binned = (int*)(T1 + NF);                          // E ints (packed)
  int*  H      = binned + E;                               // B*NB
  // d_ws layout: A (bf16 NF) + pooled
  unsigned short* Abuf = (unsigned short*)d_ws;
  float* pooled = (float*)(Abuf + NF);

  const int* src_s2t = ei_s2t;
  const int* dst_s2t = ei_s2t + E;
  const int* src_t2s = ei_t2s;
  const int* dst_t2s = ei_t2s + E;

  const int NB_T = (NT + 255) >> 8;          // dst buckets (target space)
  const int NB_S = (NS + 255) >> 8;          // dst buckets (source space)
  const int B    = (E + 4095) >> 12;         // edge chunks of 4096
  int* tot  = H + (size_t)B * ((NB_T > NB_S) ? NB_T : NB_S);  // max(NB)
  int* boff = tot + 512;

  // --- CSR build, s2t (dst in target space) ---
  bucket_hist_kernel<<<B, 256, 0, stream>>>(dst_s2t, H, E, NB_T);
  colscan_kernel<<<NB_T, 256, 0, stream>>>(H, tot, B, NB_T);
  totscan_kernel<<<1, 256, 0, stream>>>(tot, boff, NB_T);
  bin_kernel<<<B, 256, 0, stream>>>(src_s2t, dst_s2t, H, boff, binned, E, NB_T);
  build_kernel<<<NB_T, 256, 0, stream>>>(binned, boff, off_t, csr_t, inv_t, NT, NB_T, E);

  // --- CSR build, t2s (dst in source space) ---
  bucket_hist_kernel<<<B, 256, 0, stream>>>(dst_t2s, H, E, NB_S);
  colscan_kernel<<<NB_S, 256, 0, stream>>>(H, tot, B, NB_S);
  totscan_kernel<<<1, 256, 0, stream>>>(tot, boff, NB_S);
  bin_kernel<<<B, 256, 0, stream>>>(src_t2s, dst_t2s, H, boff, binned, E, NB_S);
  build_kernel<<<NB_S, 256, 0, stream>>>(binned, boff, off_s, csr_s, inv_s, NS, NB_S, E);

  // --- initial bf16 pack of layer-0 inputs + all weights ---
  int gP = (int)((NF / 4 + 255) / 256);
  pack_kernel<<<gP, 256, 0, stream>>>(x_source, S0, (int)(NF / 4));
  pack_kernel<<<gP, 256, 0, stream>>>(x_target, T0, (int)(NF / 4));
  int gW = (int)((WN / 4 + 255) / 256);
  pack_kernel<<<gW, 256, 0, stream>>>(W_l_s2t, WbLs2t, (int)(WN / 4));
  pack_kernel<<<gW, 256, 0, stream>>>(W_r_s2t, WbRs2t, (int)(WN / 4));
  pack_kernel<<<gW, 256, 0, stream>>>(W_l_t2s, WbLt2s, (int)(WN / 4));
  pack_kernel<<<gW, 256, 0, stream>>>(W_r_t2s, WbRt2s, (int)(WN / 4));

  // pooled accumulated by last-layer fgemm epilogues
  hipMemsetAsync(pooled, 0, 64 * 4, stream);

  unsigned short* xs_in = S0;
  unsigned short* xt_in = T0;
  unsigned short* xs_out = S1;
  unsigned short* xt_out = T1;

  int gS = (NS + 63) / 64;
  int gT = (NT + 63) / 64;
  int aS = (NS * 64 + 255) / 256;
  int aT = (NT * 64 + 255) / 256;

  for (int l = 0; l < L; ++l) {
    const unsigned short* Wl1 = WbLs2t + (size_t)l * 4096;
    const unsigned short* Wr1 = WbRs2t + (size_t)l * 4096;
    const float* bb1 = b_s2t + (size_t)l * 64;
    const unsigned short* Wl2 = WbLt2s + (size_t)l * 4096;
    const unsigned short* Wr2 = WbRt2s + (size_t)l * 4096;
    const float* bb2 = b_t2s + (size_t)l * 64;
    int last = (l == L - 1) ? 1 : 0;

    // conv s2t -> new xt: A = mean_agg(xs), Y = A@Wl1^T + xt@Wr1^T + b1
    agg_kernel<<<aT, 256, 0, stream>>>(xs_in, off_t, csr_t, inv_t, Abuf, NT);
    fgemm_mfma_kernel<<<gT, 256, 0, stream>>>(Abuf, xt_in, Wl1, Wr1, bb1, xt_out,
                                              pooled, NT, last);

    // conv t2s -> new xs: A = mean_agg(xt_old), Y = A@Wl2^T + xs_old@Wr2^T + b2
    agg_kernel<<<aS, 256, 0, stream>>>(xt_in, off_s, csr_s, inv_s, Abuf, NS);
    fgemm_mfma_kernel<<<gS, 256, 0, stream>>>(Abuf, xs_in, Wl2, Wr2, bb2, xs_out,
                                              pooled, NS, last);

    // swap ping-pong
    unsigned short* ts = xs_in; xs_in = xs_out; xs_out = ts;
    unsigned short* tt = xt_in; xt_in = xt_out; xt_out = tt;
  }

  final_kernel<<<1, 64, 0, stream>>>(pooled, lin_W, lin_b, (float*)d_out,
                                     1.0f / (float)(NS + NT));
}

// Round 4
// 649.298 us; speedup vs baseline: 1.5227x; 1.2120x over previous
//
#include <hip/hip_runtime.h>

// BipartiteGNN: 3-layer bipartite SAGEConv + global mean pool + linear.
// NS=NT=100000, E=1.6M per direction, F=H=64.
//
// R11: R10's MFMA fgemm was 53.7 µs with ALL pipes idle (Mfma 1%, VALU 2%,
// 247 GB/s, occ 32%) — latency/issue-bound: VGPR=36 proves the compiler
// re-loaded each weight frag right before its MFMA (serial load->wait->mfma
// x16, no reuse: every wave re-read 16 KB of weights per 16 rows), plus 16
// scalar 2B stores/thread (6.4M sub-dword stores). Fixes:
//  - weights held in 16 named bh8 regs per wave, hoisted (forces ~130 VGPR);
//  - 32 rows/wave (128/block): weight loads amortized 2x, next-subtile A/X
//    prefetched under current MFMAs;
//  - stores via LDS transpose -> fully-coalesced global_store_dwordx4
//    (2/lane/subtile, 1KB/wave-instr) instead of 16 scalar 2B stores;
//  - dispatch-count 28 -> ~14: per-layer direction pairs merged into single
//    agg2/fgemm2 dispatches; CSR-build pass pairs merged; weight packs
//    merged. A_s aliases the dead binned_t+binned_s region (exactly 12.8MB).
// agg_kernel body is the R7-proven one (55 µs, 3 TB/s, occ 70%), unchanged.

#define FDIM 64

typedef short bh8 __attribute__((ext_vector_type(8)));  // 8 bf16 = 4 VGPR
typedef float fx4 __attribute__((ext_vector_type(4)));  // MFMA accumulator

__device__ __forceinline__ unsigned short f2bf(float f) {
  unsigned int u = __float_as_uint(f);
  unsigned int r = u + 0x7FFFu + ((u >> 16) & 1u);  // round-to-nearest-even
  return (unsigned short)(r >> 16);
}
__device__ __forceinline__ float bf2f(unsigned short h) {
  return __uint_as_float((unsigned int)h << 16);
}

// ---------------- CSR build (bucketed, atomic-free at global scope) ----------------
// Each pass handles BOTH directions in one dispatch (blockIdx selects).

// Pass 1: per-block histogram over dst>>8 buckets. Block = 4096 edges.
__global__ __launch_bounds__(256) void hist2_kernel(const int* __restrict__ dstT,
                                                    int* __restrict__ HT, int NBT,
                                                    const int* __restrict__ dstS,
                                                    int* __restrict__ HS, int NBS,
                                                    int E, int B) {
  __shared__ int lh[512];
  int b = blockIdx.x;
  const int* dst;
  int* H;
  int NB;
  if (b < B) {
    dst = dstT; H = HT; NB = NBT;
  } else {
    b -= B; dst = dstS; H = HS; NB = NBS;
  }
  int t = threadIdx.x;
  lh[t] = 0;
  lh[t + 256] = 0;
  __syncthreads();
  int base = b * 4096;
#pragma unroll
  for (int i = 0; i < 16; ++i) {
    int e = base + i * 256 + t;
    if (e < E) atomicAdd(&lh[dst[e] >> 8], 1);
  }
  __syncthreads();
  int* row = H + (size_t)b * NB;
  if (t < NB) row[t] = lh[t];
  if (t + 256 < NB) row[t + 256] = lh[t + 256];
}

// Pass 2a: per bucket k, exclusive-scan H[:,k] over B rows; tot[k] = total.
__global__ __launch_bounds__(256) void colscan2_kernel(int* __restrict__ HT,
                                                       int* __restrict__ totT, int NBT,
                                                       int* __restrict__ HS,
                                                       int* __restrict__ totS, int NBS,
                                                       int B) {
  __shared__ int sh[512];
  int k = blockIdx.x;
  int* H;
  int* tot;
  int NB;
  if (k < NBT) {
    H = HT; tot = totT; NB = NBT;
  } else {
    k -= NBT; H = HS; tot = totS; NB = NBS;
  }
  int t = threadIdx.x;
  int v0 = (t < B) ? H[(size_t)t * NB + k] : 0;
  int v1 = (t + 256 < B) ? H[(size_t)(t + 256) * NB + k] : 0;
  sh[t] = v0;
  sh[t + 256] = v1;
  __syncthreads();
  for (int d = 1; d < 512; d <<= 1) {
    int a0 = (t >= d) ? sh[t - d] : 0;
    int a1 = (t + 256 >= d) ? sh[t + 256 - d] : 0;
    __syncthreads();
    sh[t] += a0;
    sh[t + 256] += a1;
    __syncthreads();
  }
  if (t < B) H[(size_t)t * NB + k] = sh[t] - v0;  // exclusive
  if (t + 256 < B) H[(size_t)(t + 256) * NB + k] = sh[t + 256] - v1;
  if (t == 0) tot[k] = sh[511];
}

// Pass 2b: exclusive scan of bucket totals -> boff. One block per direction.
__global__ __launch_bounds__(256) void totscan2_kernel(const int* __restrict__ totT,
                                                       int* __restrict__ boffT, int NBT,
                                                       const int* __restrict__ totS,
                                                       int* __restrict__ boffS, int NBS) {
  __shared__ int sh[512];
  const int* tot = (blockIdx.x == 0) ? totT : totS;
  int* boff = (blockIdx.x == 0) ? boffT : boffS;
  int NB = (blockIdx.x == 0) ? NBT : NBS;
  int t = threadIdx.x;
  sh[t] = (t < NB) ? tot[t] : 0;
  sh[t + 256] = (t + 256 < NB) ? tot[t + 256] : 0;
  __syncthreads();
  for (int d = 1; d < 512; d <<= 1) {
    int a0 = (t >= d) ? sh[t - d] : 0;
    int a1 = (t + 256 >= d) ? sh[t + 256 - d] : 0;
    __syncthreads();
    sh[t] += a0;
    sh[t + 256] += a1;
    __syncthreads();
  }
  if (t < NB) boff[t] = (t > 0) ? sh[t - 1] : 0;
  if (t + 256 < NB) boff[t + 256] = sh[t + 255];
}

// Pass 3: scatter edges into bucket-grouped order.
// Entry packed: (src << 8) | (dst & 255)
__global__ __launch_bounds__(256) void bin2_kernel(const int* __restrict__ srcT,
                                                   const int* __restrict__ dstT,
                                                   const int* __restrict__ HT,
                                                   const int* __restrict__ boffT,
                                                   int* __restrict__ binnedT, int NBT,
                                                   const int* __restrict__ srcS,
                                                   const int* __restrict__ dstS,
                                                   const int* __restrict__ HS,
                                                   const int* __restrict__ boffS,
                                                   int* __restrict__ binnedS, int NBS,
                                                   int E, int B) {
  __shared__ int cur[512];
  int b = blockIdx.x;
  const int *src, *dst, *H, *boff;
  int* binned;
  int NB;
  if (b < B) {
    src = srcT; dst = dstT; H = HT; boff = boffT; binned = binnedT; NB = NBT;
  } else {
    b -= B; src = srcS; dst = dstS; H = HS; boff = boffS; binned = binnedS; NB = NBS;
  }
  int t = threadIdx.x;
  const int* row = H + (size_t)b * NB;
  if (t < NB) cur[t] = row[t] + boff[t];
  if (t + 256 < NB) cur[t + 256] = row[t + 256] + boff[t + 256];
  __syncthreads();
  int base = b * 4096;
#pragma unroll
  for (int i = 0; i < 16; ++i) {
    int e = base + i * 256 + t;
    if (e < E) {
      int d = dst[e];
      int p = atomicAdd(&cur[d >> 8], 1);  // LDS atomic
      binned[p] = (src[e] << 8) | (d & 255);
    }
  }
}

// Pass 4: one block per bucket -> local hist/scan/rank, contiguous CSR slab.
__global__ __launch_bounds__(256) void build2_kernel(const int* __restrict__ binnedT,
                                                     const int* __restrict__ boffT,
                                                     int* __restrict__ offT,
                                                     int* __restrict__ csrT,
                                                     float* __restrict__ invT,
                                                     int NT, int NBT,
                                                     const int* __restrict__ binnedS,
                                                     const int* __restrict__ boffS,
                                                     int* __restrict__ offS,
                                                     int* __restrict__ csrS,
                                                     float* __restrict__ invS,
                                                     int NS, int NBS, int E) {
  __shared__ int cnt[256];
  __shared__ int lofs[256];
  __shared__ int cur[256];
  int b = blockIdx.x;
  const int *binned, *boff;
  int *off, *csr;
  float* inv_deg;
  int N, NB;
  if (b < NBT) {
    binned = binnedT; boff = boffT; off = offT; csr = csrT; inv_deg = invT;
    N = NT; NB = NBT;
  } else {
    b -= NBT;
    binned = binnedS; boff = boffS; off = offS; csr = csrS; inv_deg = invS;
    N = NS; NB = NBS;
  }
  int t = threadIdx.x;
  int n0 = b << 8;
  cnt[t] = 0;
  __syncthreads();
  int s0 = boff[b];
  int s1 = (b + 1 < NB) ? boff[b + 1] : E;
  for (int i = s0 + t; i < s1; i += 256) {
    atomicAdd(&cnt[binned[i] & 255], 1);  // LDS atomic
  }
  __syncthreads();
  int c = cnt[t];
  lofs[t] = c;
  __syncthreads();
  for (int d = 1; d < 256; d <<= 1) {
    int v = (t >= d) ? lofs[t - d] : 0;
    __syncthreads();
    lofs[t] += v;
    __syncthreads();
  }
  int excl = lofs[t] - c;
  cur[t] = s0 + excl;
  int node = n0 + t;
  if (node < N) {
    off[node] = s0 + excl;
    inv_deg[node] = 1.0f / (float)max(c, 1);
    if (node == N - 1) off[N] = s0 + excl + c;
  }
  __syncthreads();
  for (int i = s0 + t; i < s1; i += 256) {
    int e = binned[i];
    int r = atomicAdd(&cur[e & 255], 1);  // LDS atomic
    csr[r] = e >> 8;
  }
}

// ---------------- fp32 -> bf16 pack ----------------

__global__ void pack_kernel(const float* __restrict__ X, unsigned short* __restrict__ Y, int n4) {
  int i = blockIdx.x * 256 + threadIdx.x;
  if (i < n4) {
    float4 v = ((const float4*)X)[i];
    uint2 pk;
    pk.x = (unsigned int)f2bf(v.x) | ((unsigned int)f2bf(v.y) << 16);
    pk.y = (unsigned int)f2bf(v.z) | ((unsigned int)f2bf(v.w) << 16);
    ((uint2*)Y)[i] = pk;
  }
}

// Pack 4 equal-size arrays in one dispatch (weights).
__global__ void pack4_kernel(const float* __restrict__ X0, unsigned short* __restrict__ Y0,
                             const float* __restrict__ X1, unsigned short* __restrict__ Y1,
                             const float* __restrict__ X2, unsigned short* __restrict__ Y2,
                             const float* __restrict__ X3, unsigned short* __restrict__ Y3,
                             int n4, int gPer) {
  int seg = blockIdx.x / gPer;
  int i = (blockIdx.x - seg * gPer) * 256 + threadIdx.x;
  const float* X = (seg == 0) ? X0 : (seg == 1) ? X1 : (seg == 2) ? X2 : X3;
  unsigned short* Y = (seg == 0) ? Y0 : (seg == 1) ? Y1 : (seg == 2) ? Y2 : Y3;
  if (i < n4) {
    float4 v = ((const float4*)X)[i];
    uint2 pk;
    pk.x = (unsigned int)f2bf(v.x) | ((unsigned int)f2bf(v.y) << 16);
    pk.y = (unsigned int)f2bf(v.z) | ((unsigned int)f2bf(v.w) << 16);
    ((uint2*)Y)[i] = pk;
  }
}

// ---------------- aggregation (both directions, one dispatch) ----------------
// R7-proven body: one wave per dst node; 4 groups of 16 lanes, uint2 loads,
// wave-uniform inner trip count (every __shfl sees all 64 lanes active).

__global__ __launch_bounds__(256) void agg2_kernel(
    const unsigned short* __restrict__ MsgT, const int* __restrict__ offT,
    const int* __restrict__ csrT, const float* __restrict__ invT,
    unsigned short* __restrict__ AT, int NT, int gT,
    const unsigned short* __restrict__ MsgS, const int* __restrict__ offS,
    const int* __restrict__ csrS, const float* __restrict__ invS,
    unsigned short* __restrict__ AS, int NS) {
  int b = blockIdx.x;
  const unsigned short* Msg;
  const int *off, *csr;
  const float* inv_deg;
  unsigned short* A;
  int N;
  if (b < gT) {
    Msg = MsgT; off = offT; csr = csrT; inv_deg = invT; A = AT; N = NT;
  } else {
    b -= gT;
    Msg = MsgS; off = offS; csr = csrS; inv_deg = invS; A = AS; N = NS;
  }
  int w = (b * 256 + threadIdx.x) >> 6;
  int lane = threadIdx.x & 63;
  if (w >= N) return;
  int g = lane >> 4;    // edge group 0..3
  int fl = lane & 15;   // feature sublane: features [fl*4, fl*4+4)
  int s0 = off[w], s1 = off[w + 1];
  float ax = 0.f, ay = 0.f, az = 0.f, aw = 0.f;
  for (int base = s0; base < s1; base += 64) {
    int idx = base + lane;
    int mysrc = (idx < s1) ? csr[idx] : 0;
    int m = min(64, s1 - base);
    int kmax = (m + 3) >> 2;  // wave-uniform
    for (int k = 0; k < kmax; ++k) {
      int j = g + 4 * k;
      int s = __shfl(mysrc, (j < m) ? j : 0, 64);  // all 64 lanes active here
      if (j < m) {
        uint2 v = *((const uint2*)(Msg + (size_t)s * 64) + fl);
        ax += bf2f((unsigned short)(v.x & 0xffffu));
        ay += bf2f((unsigned short)(v.x >> 16));
        az += bf2f((unsigned short)(v.y & 0xffffu));
        aw += bf2f((unsigned short)(v.y >> 16));
      }
    }
  }
  ax += __shfl_down(ax, 32, 64);
  ay += __shfl_down(ay, 32, 64);
  az += __shfl_down(az, 32, 64);
  aw += __shfl_down(aw, 32, 64);
  ax += __shfl_down(ax, 16, 64);
  ay += __shfl_down(ay, 16, 64);
  az += __shfl_down(az, 16, 64);
  aw += __shfl_down(aw, 16, 64);
  if (g == 0) {
    float id = inv_deg[w];
    uint2 pk;
    pk.x = (unsigned int)f2bf(ax * id) | ((unsigned int)f2bf(ay * id) << 16);
    pk.y = (unsigned int)f2bf(az * id) | ((unsigned int)f2bf(aw * id) << 16);
    *((uint2*)(A + (size_t)w * 64) + fl) = pk;
  }
}

// ---------------- MFMA dual GEMM v2 (both directions, one dispatch) ----------------
// Block = 4 waves x 32 rows = 128 rows. Per wave: all 16 weight B-frags in
// named registers (hoisted, ~64 VGPR); 2 subtiles of 16 rows with the next
// subtile's A/X loads prefetched under the current MFMAs; epilogue adds bias
// in-register, transposes the C-frag through a per-wave LDS tile, and emits
// fully-coalesced global_store_dwordx4 (2 per lane per subtile, 1KB/instr).
// Last layer reduces into pooled[] instead of storing Y.

__global__ __launch_bounds__(256) void fgemm2_kernel(
    const unsigned short* __restrict__ A1, const unsigned short* __restrict__ X1,
    const unsigned short* __restrict__ Wl1, const unsigned short* __restrict__ Wr1,
    const float* __restrict__ bias1, unsigned short* __restrict__ Y1, int N1,
    const unsigned short* __restrict__ A2, const unsigned short* __restrict__ X2,
    const unsigned short* __restrict__ Wl2, const unsigned short* __restrict__ Wr2,
    const float* __restrict__ bias2, unsigned short* __restrict__ Y2, int N2,
    int g1, float* __restrict__ pooled, int lastLayer) {
  __shared__ __align__(16) float st[4][16][68];  // per-wave C transpose tile
  __shared__ float pacc[64];
  int bid = blockIdx.x;
  const unsigned short *A, *X, *Wlb, *Wrb;
  const float* bias;
  unsigned short* Y;
  int N;
  if (bid < g1) {
    A = A1; X = X1; Wlb = Wl1; Wrb = Wr1; bias = bias1; Y = Y1; N = N1;
  } else {
    bid -= g1;
    A = A2; X = X2; Wlb = Wl2; Wrb = Wr2; bias = bias2; Y = Y2; N = N2;
  }
  int t = threadIdx.x;
  if (lastLayer) {
    if (t < 64) pacc[t] = 0.f;
    __syncthreads();
  }
  int wid = t >> 6, lane = t & 63;
  int lr = lane & 15;  // row within A/B frag; col (=h) within C frag
  int kg = lane >> 4;  // k-subgroup 0..3
  int m0 = bid * 128 + wid * 32;

  const bh8* wl = (const bh8*)Wlb;
  const bh8* wr = (const bh8*)Wrb;
  // all 16 weight fragments live for the whole kernel
  bh8 bl0[4], bl1[4], br0[4], br1[4];
#pragma unroll
  for (int nt = 0; nt < 4; ++nt) {
    bl0[nt] = wl[(nt * 16 + lr) * 8 + kg];
    bl1[nt] = wl[(nt * 16 + lr) * 8 + 4 + kg];
    br0[nt] = wr[(nt * 16 + lr) * 8 + kg];
    br1[nt] = wr[(nt * 16 + lr) * 8 + 4 + kg];
  }
  float bias_r[4];
#pragma unroll
  for (int nt = 0; nt < 4; ++nt) bias_r[nt] = bias[nt * 16 + lr];

  // prefetch subtile 0 rows
  int mr = min(m0 + lr, N - 1);
  const bh8* ar = (const bh8*)(A + (size_t)mr * 64);
  const bh8* xr = (const bh8*)(X + (size_t)mr * 64);
  bh8 a0 = ar[kg], a1 = ar[4 + kg], x0 = xr[kg], x1 = xr[4 + kg];

  float psum[4] = {0.f, 0.f, 0.f, 0.f};

#pragma unroll
  for (int sub = 0; sub < 2; ++sub) {
    bh8 na0 = a0, na1 = a1, nx0 = x0, nx1 = x1;
    if (sub == 0) {  // prefetch subtile 1 under this subtile's MFMAs
      int mr1 = min(m0 + 16 + lr, N - 1);
      const bh8* ar1 = (const bh8*)(A + (size_t)mr1 * 64);
      const bh8* xr1 = (const bh8*)(X + (size_t)mr1 * 64);
      na0 = ar1[kg]; na1 = ar1[4 + kg]; nx0 = xr1[kg]; nx1 = xr1[4 + kg];
    }
    fx4 acc[4];
#pragma unroll
    for (int nt = 0; nt < 4; ++nt) acc[nt] = (fx4){0.f, 0.f, 0.f, 0.f};
#pragma unroll
    for (int nt = 0; nt < 4; ++nt)
      acc[nt] = __builtin_amdgcn_mfma_f32_16x16x32_bf16(a0, bl0[nt], acc[nt], 0, 0, 0);
#pragma unroll
    for (int nt = 0; nt < 4; ++nt)
      acc[nt] = __builtin_amdgcn_mfma_f32_16x16x32_bf16(a1, bl1[nt], acc[nt], 0, 0, 0);
#pragma unroll
    for (int nt = 0; nt < 4; ++nt)
      acc[nt] = __builtin_amdgcn_mfma_f32_16x16x32_bf16(x0, br0[nt], acc[nt], 0, 0, 0);
#pragma unroll
    for (int nt = 0; nt < 4; ++nt)
      acc[nt] = __builtin_amdgcn_mfma_f32_16x16x32_bf16(x1, br1[nt], acc[nt], 0, 0, 0);

    int mbase = m0 + sub * 16;
    if (!lastLayer) {
      // stage C (bias added) into per-wave LDS tile: row = kg*4+j, col = h
#pragma unroll
      for (int nt = 0; nt < 4; ++nt)
#pragma unroll
        for (int j = 0; j < 4; ++j)
          st[wid][kg * 4 + j][nt * 16 + lr] = acc[nt][j] + bias_r[nt];
      // read back row-major (compiler inserts lgkmcnt waits; per-wave tile,
      // no cross-wave sharing -> no __syncthreads)
#pragma unroll
      for (int s = 0; s < 2; ++s) {
        int chunk = lane + 64 * s;  // 16 rows x 8 chunks of 8 h
        int r = chunk >> 3, c = chunk & 7;
        float4 v0 = *(const float4*)&st[wid][r][c * 8];
        float4 v1 = *(const float4*)&st[wid][r][c * 8 + 4];
        uint4 pk;
        pk.x = (unsigned int)f2bf(v0.x) | ((unsigned int)f2bf(v0.y) << 16);
        pk.y = (unsigned int)f2bf(v0.z) | ((unsigned int)f2bf(v0.w) << 16);
        pk.z = (unsigned int)f2bf(v1.x) | ((unsigned int)f2bf(v1.y) << 16);
        pk.w = (unsigned int)f2bf(v1.z) | ((unsigned int)f2bf(v1.w) << 16);
        int m = mbase + r;
        if (m < N) ((uint4*)(Y + (size_t)m * 64))[c] = pk;
      }
    } else {
      // pooled-only epilogue: no Y write
#pragma unroll
      for (int nt = 0; nt < 4; ++nt) {
        float sacc = 0.f;
#pragma unroll
        for (int j = 0; j < 4; ++j) {
          int m = mbase + kg * 4 + j;
          if (m < N) sacc += acc[nt][j] + bias_r[nt];
        }
        psum[nt] += sacc;
      }
    }
    a0 = na0; a1 = na1; x0 = nx0; x1 = nx1;
  }

  if (lastLayer) {
#pragma unroll
    for (int nt = 0; nt < 4; ++nt) atomicAdd(&pacc[nt * 16 + lr], psum[nt]);
    __syncthreads();
    if (t < 64) atomicAdd(&pooled[t], pacc[t]);
  }
}

// ---------------- final linear ----------------

__global__ void final_kernel(const float* __restrict__ pooled, const float* __restrict__ linW,
                             const float* __restrict__ linb, float* __restrict__ out, float invM) {
  int t = threadIdx.x;  // 64 threads
  float v = pooled[t] * invM * linW[t];
#pragma unroll
  for (int o = 32; o > 0; o >>= 1) v += __shfl_down(v, o, 64);
  if (t == 0) out[0] = v + linb[0];
}

// ---------------- launch ----------------

extern "C" void kernel_launch(void* const* d_in, const int* in_sizes, int n_in,
                              void* d_out, int out_size, void* d_ws, size_t ws_size,
                              hipStream_t stream) {
  const float* x_source = (const float*)d_in[0];
  const float* x_target = (const float*)d_in[1];
  float* scratchA = (float*)d_in[2];  // edge_attr_s2t: 12.8M floats, unused input
  float* scratchB = (float*)d_in[3];  // edge_attr_t2s: 12.8M floats, unused input
  const float* W_l_s2t = (const float*)d_in[4];
  const float* b_s2t   = (const float*)d_in[5];
  const float* W_r_s2t = (const float*)d_in[6];
  const float* W_l_t2s = (const float*)d_in[7];
  const float* b_t2s   = (const float*)d_in[8];
  const float* W_r_t2s = (const float*)d_in[9];
  const float* lin_W   = (const float*)d_in[10];
  const float* lin_b   = (const float*)d_in[11];
  const int* ei_s2t    = (const int*)d_in[12];
  const int* ei_t2s    = (const int*)d_in[13];

  const int NS = in_sizes[0] / FDIM;
  const int NT = in_sizes[1] / FDIM;
  const int E  = in_sizes[12] / 2;
  const int L  = in_sizes[4] / (FDIM * FDIM);
  const size_t NF = (size_t)NS * FDIM;        // 6.4M elems
  const size_t WN = (size_t)L * FDIM * FDIM;  // per weight array, elems

  // scratchA: S0, T0 (bf16 NF), Wb x4, csr_t, csr_s, inv_t, inv_s, off_t, off_s
  unsigned short* S0 = (unsigned short*)scratchA;          // NF bf16
  unsigned short* T0 = S0 + NF;                            // NF bf16
  unsigned short* WbLs2t = T0 + NF;                        // L*4096 bf16
  unsigned short* WbRs2t = WbLs2t + WN;
  unsigned short* WbLt2s = WbRs2t + WN;
  unsigned short* WbRt2s = WbLt2s + WN;
  int*   csr_t  = (int*)(WbRt2s + WN);        // E
  int*   csr_s  = csr_t + E;                  // E
  float* inv_t  = (float*)(csr_s + E);        // NS
  float* inv_s  = inv_t + NS;                 // NS
  int*   off_t  = (int*)(inv_s + NS);         // NS+1
  int*   off_s  = off_t + NS + 1;             // NS+1

  const int NB_T = (NT + 255) >> 8;
  const int NB_S = (NS + 255) >> 8;
  const int B    = (E + 4095) >> 12;

  // scratchB: S1, T1, binned_t, binned_s, H_t, H_s, tot/boff x2
  unsigned short* S1 = (unsigned short*)scratchB;          // NF bf16
  unsigned short* T1 = S1 + NF;                            // NF bf16
  int* binned_t = (int*)(T1 + NF);                         // E
  int* binned_s = binned_t + E;                            // E
  int* H_t      = binned_s + E;                            // B*NB_T
  int* H_s      = H_t + (size_t)B * NB_T;                  // B*NB_S
  int* tot_t    = H_s + (size_t)B * NB_S;                  // 512
  int* boff_t   = tot_t + 512;                             // 512
  int* tot_s    = boff_t + 512;                            // 512
  int* boff_s   = tot_s + 512;                             // 512
  // A_s aliases binned_t+binned_s (dead after build; 2*E*4 == NF*2 bytes)
  unsigned short* As = (unsigned short*)binned_t;

  // d_ws: A_t (bf16 NF) + pooled
  unsigned short* At = (unsigned short*)d_ws;
  float* pooled = (float*)(At + NF);

  const int* src_s2t = ei_s2t;
  const int* dst_s2t = ei_s2t + E;
  const int* src_t2s = ei_t2s;
  const int* dst_t2s = ei_t2s + E;

  // --- CSR build, both directions per pass ---
  hist2_kernel<<<2 * B, 256, 0, stream>>>(dst_s2t, H_t, NB_T, dst_t2s, H_s, NB_S, E, B);
  colscan2_kernel<<<NB_T + NB_S, 256, 0, stream>>>(H_t, tot_t, NB_T, H_s, tot_s, NB_S, B);
  totscan2_kernel<<<2, 256, 0, stream>>>(tot_t, boff_t, NB_T, tot_s, boff_s, NB_S);
  bin2_kernel<<<2 * B, 256, 0, stream>>>(src_s2t, dst_s2t, H_t, boff_t, binned_t, NB_T,
                                         src_t2s, dst_t2s, H_s, boff_s, binned_s, NB_S, E, B);
  build2_kernel<<<NB_T + NB_S, 256, 0, stream>>>(binned_t, boff_t, off_t, csr_t, inv_t, NT, NB_T,
                                                 binned_s, boff_s, off_s, csr_s, inv_s, NS, NB_S, E);

  // --- bf16 packs: features (2 dispatches) + all weights (1 dispatch) ---
  int gP = (int)((NF / 4 + 255) / 256);
  pack_kernel<<<gP, 256, 0, stream>>>(x_source, S0, (int)(NF / 4));
  pack_kernel<<<gP, 256, 0, stream>>>(x_target, T0, (int)(NF / 4));
  int n4W = (int)(WN / 4);
  int gW = (n4W + 255) / 256;
  pack4_kernel<<<4 * gW, 256, 0, stream>>>(W_l_s2t, WbLs2t, W_r_s2t, WbRs2t,
                                           W_l_t2s, WbLt2s, W_r_t2s, WbRt2s, n4W, gW);

  hipMemsetAsync(pooled, 0, 64 * 4, stream);

  unsigned short* xs_in = S0;
  unsigned short* xt_in = T0;
  unsigned short* xs_out = S1;
  unsigned short* xt_out = T1;

  int aT = (NT * 64 + 255) / 256;  // agg blocks (4 nodes/block)
  int aS = (NS * 64 + 255) / 256;
  int gT2 = (NT + 127) / 128;      // fgemm2 blocks (128 rows/block)
  int gS2 = (NS + 127) / 128;

  for (int l = 0; l < L; ++l) {
    const unsigned short* Wl1 = WbLs2t + (size_t)l * 4096;
    const unsigned short* Wr1 = WbRs2t + (size_t)l * 4096;
    const float* bb1 = b_s2t + (size_t)l * 64;
    const unsigned short* Wl2 = WbLt2s + (size_t)l * 4096;
    const unsigned short* Wr2 = WbRt2s + (size_t)l * 4096;
    const float* bb2 = b_t2s + (size_t)l * 64;
    int last = (l == L - 1) ? 1 : 0;

    // A_t = mean_agg(xs_in) over s2t CSR; A_s = mean_agg(xt_in) over t2s CSR
    agg2_kernel<<<aT + aS, 256, 0, stream>>>(xs_in, off_t, csr_t, inv_t, At, NT, aT,
                                             xt_in, off_s, csr_s, inv_s, As, NS);
    // xt_out = A_t@Wl1^T + xt_in@Wr1^T + b1 ; xs_out = A_s@Wl2^T + xs_in@Wr2^T + b2
    fgemm2_kernel<<<gT2 + gS2, 256, 0, stream>>>(At, xt_in, Wl1, Wr1, bb1, xt_out, NT,
                                                 As, xs_in, Wl2, Wr2, bb2, xs_out, NS,
                                                 gT2, pooled, last);

    unsigned short* ts = xs_in; xs_in = xs_out; xs_out = ts;
    unsigned short* tt = xt_in; xt_in = xt_out; xt_out = tt;
  }

  final_kernel<<<1, 64, 0, stream>>>(pooled, lin_W, lin_b, (float*)d_out,
                                     1.0f / (float)(NS + NT));
}